// Round 4
// baseline (75.309 us; speedup 1.0000x reference)
//
#include <hip/hip_runtime.h>
#include <hip/hip_bf16.h>

#define TSEQ 256
#define NBATCH 2
#define NAG 8
#define NH 8
#define HD 64
#define EE 512
#define WHALF 16
#define WW 33
#define WN 264   // WW*NAG

typedef __attribute__((ext_vector_type(8))) short short8;
typedef __attribute__((ext_vector_type(4))) short short4v;
typedef __attribute__((ext_vector_type(4))) float f32x4;

static __device__ __forceinline__ unsigned short f2bf(float f) {
    unsigned int u = __float_as_uint(f);
    unsigned int r = (u + 0x7FFFu + ((u >> 16) & 1u)) >> 16;
    return (unsigned short)r;
}

// ---------------- fused QKV projection GEMM (bf16 MFMA) -----------------
// BM=128, BN=128, BK=64, 4 waves (2x2, 64x64 each). z picks {q,k,v}.
// z==2 (v) writes TRANSPOSED vt[b][h][d][key=t*8+m] for attn PV B-fragments.
__global__ __launch_bounds__(256)
void proj_mfma_kernel(const float* __restrict__ xq, const float* __restrict__ xk,
                      const float* __restrict__ xv,
                      const float* __restrict__ Wq, const float* __restrict__ Wk,
                      const float* __restrict__ Wv,
                      const float* __restrict__ bq, const float* __restrict__ bk,
                      const float* __restrict__ bv,
                      unsigned short* __restrict__ oq, unsigned short* __restrict__ ok,
                      unsigned short* __restrict__ vt)
{
    __shared__ char As[128 * 128];   // 128 rows x 64 bf16 (swizzled)
    __shared__ char Bs[128 * 128];

    const float* x; const float* W; const float* bias; float scale;
    const int z = blockIdx.z;
    if (z == 0)      { x = xq; W = Wq; bias = bq; scale = 0.125f; }
    else if (z == 1) { x = xk; W = Wk; bias = bk; scale = 1.0f; }
    else             { x = xv; W = Wv; bias = bv; scale = 1.0f; }

    const int tid  = threadIdx.x;
    const int lane = tid & 63;
    const int wid  = tid >> 6;
    const int i0 = blockIdx.x * 128;
    const int f0 = blockIdx.y * 128;
    const int wr = wid >> 1, wc = wid & 1;

    f32x4 acc[4][4];
    #pragma unroll
    for (int m = 0; m < 4; ++m)
        #pragma unroll
        for (int n = 0; n < 4; ++n)
            acc[m][n] = (f32x4){0.f, 0.f, 0.f, 0.f};

    for (int k0 = 0; k0 < EE; k0 += 64) {
        #pragma unroll
        for (int it = 0; it < 8; ++it) {
            const int tt  = tid + it * 256;        // 0..2047
            const int row = tt >> 4, f4 = tt & 15;
            float4 v4 = *reinterpret_cast<const float4*>(x + (size_t)(i0 + row) * EE + k0 + f4 * 4);
            short4v s;
            s[0] = (short)f2bf(v4.x); s[1] = (short)f2bf(v4.y);
            s[2] = (short)f2bf(v4.z); s[3] = (short)f2bf(v4.w);
            *(short4v*)(As + row * 128 + ((f4 * 8) ^ ((row & 7) << 4))) = s;
        }
        #pragma unroll
        for (int it = 0; it < 8; ++it) {
            const int tt  = tid + it * 256;
            const int row = tt >> 4, f4 = tt & 15;
            float4 v4 = *reinterpret_cast<const float4*>(W + (size_t)(f0 + row) * EE + k0 + f4 * 4);
            short4v s;
            s[0] = (short)f2bf(v4.x); s[1] = (short)f2bf(v4.y);
            s[2] = (short)f2bf(v4.z); s[3] = (short)f2bf(v4.w);
            *(short4v*)(Bs + row * 128 + ((f4 * 8) ^ ((row & 7) << 4))) = s;
        }
        __syncthreads();

        #pragma unroll
        for (int ks = 0; ks < 2; ++ks) {
            short8 a[4], b[4];
            #pragma unroll
            for (int m = 0; m < 4; ++m) {
                const int row = wr * 64 + m * 16 + (lane & 15);
                a[m] = *(short8*)(As + row * 128 +
                                  ((ks * 64 + (lane >> 4) * 16) ^ ((row & 7) << 4)));
            }
            #pragma unroll
            for (int n = 0; n < 4; ++n) {
                const int row = wc * 64 + n * 16 + (lane & 15);
                b[n] = *(short8*)(Bs + row * 128 +
                                  ((ks * 64 + (lane >> 4) * 16) ^ ((row & 7) << 4)));
            }
            #pragma unroll
            for (int m = 0; m < 4; ++m)
                #pragma unroll
                for (int n = 0; n < 4; ++n)
                    acc[m][n] = __builtin_amdgcn_mfma_f32_16x16x32_bf16(a[m], b[n], acc[m][n], 0, 0, 0);
        }
        __syncthreads();
    }

    if (z < 2) {
        unsigned short* o = (z == 0) ? oq : ok;
        #pragma unroll
        for (int n = 0; n < 4; ++n) {
            const int col = f0 + wc * 64 + n * 16 + (lane & 15);
            const float bb = bias[col];
            #pragma unroll
            for (int m = 0; m < 4; ++m)
                #pragma unroll
                for (int rg = 0; rg < 4; ++rg) {
                    const int row = i0 + wr * 64 + m * 16 + (lane >> 4) * 4 + rg;
                    o[(size_t)row * EE + col] = f2bf((acc[m][n][rg] + bb) * scale);
                }
        }
    } else {
        // transposed store: vt[((b*8+h)*64+d)*2048 + (t*8+m)]
        #pragma unroll
        for (int n = 0; n < 4; ++n) {
            const int col = f0 + wc * 64 + n * 16 + (lane & 15);
            const int h = col >> 6, d = col & 63;
            const float bb = bias[col];
            #pragma unroll
            for (int m = 0; m < 4; ++m) {
                const int ibase = i0 + wr * 64 + m * 16 + (lane >> 4) * 4;
                const int bb_ = ibase >> 11;          // batch
                const int key = ibase & 2047;
                ushort4 s4;
                s4.x = f2bf(acc[m][n][0] + bb);
                s4.y = f2bf(acc[m][n][1] + bb);
                s4.z = f2bf(acc[m][n][2] + bb);
                s4.w = f2bf(acc[m][n][3] + bb);
                *(ushort4*)(vt + ((size_t)(bb_ * 8 + h) * 64 + d) * 2048 + key) = s4;
            }
        }
    }
}

// ---------------- MFMA windowed attention (no K/Q/V staging) -----------------
// grid: 1024 blocks; bid = ts*16 + (h*2+b), ts = t-tile of 4. 512 threads.
#define PROW 300                     // floats per P row (1200 B)
#define KM_OFF (32 * 1200)
#define SMEM2_BYTES (KM_OFF + 384)

__global__ __launch_bounds__(512)
void attn_mfma_kernel(const unsigned short* __restrict__ qb,
                      const unsigned short* __restrict__ kb,
                      const unsigned short* __restrict__ vt,
                      const unsigned char* __restrict__ kpm,
                      float* __restrict__ out,
                      float* __restrict__ attn)
{
    __shared__ char smem[SMEM2_BYTES];
    float* P32 = (float*)smem;

    const int bid = blockIdx.x;
    const int idx = bid & 15;
    const int ts  = bid >> 4;
    const int h = idx >> 1;
    const int b = idx & 1;
    const int t00 = ts * 4;
    const int j0  = t00 - WHALF;          // 36 j's -> 288 local keys
    const int tid = threadIdx.x;
    const int lane = tid & 63;
    const int wid  = tid >> 6;

    // ---- key-valid mask (read in softmax after barrier) ----
    if (tid < 288) {
        const int jj = tid >> 3, m = tid & 7;
        const int j = j0 + jj;
        smem[KM_OFF + tid] = (j >= 0 && j < TSEQ && kpm[(b * TSEQ + j) * NAG + m] == 0) ? 1 : 0;
    }

    // ---- QK^T: D[32 x 288] from global fragments ----
    {
        const int rfrag = wid & 1;                     // wave's parity fixes rfrag
        const int arow = rfrag * 16 + (lane & 15);
        const int t = t00 + (arow >> 3), n = arow & 7;
        const unsigned short* qbase = qb + ((size_t)(b * TSEQ + t) * NAG + n) * EE + h * HD;
        short8 aq0 = *(const short8*)(qbase + (lane >> 4) * 8);
        short8 aq1 = *(const short8*)(qbase + 32 + (lane >> 4) * 8);

        #pragma unroll
        for (int i = 0; i < 5; ++i) {
            const int cf = (wid >> 1) + 4 * i;         // pair p = wid + 8*i
            if (cf >= 18) break;
            const int krow = cf * 16 + (lane & 15);
            int j = j0 + (krow >> 3);
            j = (j < 0) ? 0 : ((j > TSEQ - 1) ? TSEQ - 1 : j);
            const int m = krow & 7;
            const unsigned short* kbase = kb + ((size_t)(b * TSEQ + j) * NAG + m) * EE + h * HD;
            f32x4 a = (f32x4){0.f, 0.f, 0.f, 0.f};
            a = __builtin_amdgcn_mfma_f32_16x16x32_bf16(aq0, *(const short8*)(kbase + (lane >> 4) * 8), a, 0, 0, 0);
            a = __builtin_amdgcn_mfma_f32_16x16x32_bf16(aq1, *(const short8*)(kbase + 32 + (lane >> 4) * 8), a, 0, 0, 0);
            const int col = cf * 16 + (lane & 15);
            const int r0 = rfrag * 16 + (lane >> 4) * 4;
            #pragma unroll
            for (int rg = 0; rg < 4; ++rg)
                P32[(r0 + rg) * PROW + col] = a[rg];
        }
    }
    __syncthreads();

    // ---- softmax over 264-window + attn store + bf16 repack ----
    {
        const int rr = tid >> 4, s16 = tid & 15;
        const int dt = rr >> 3, n = rr & 7;
        const int t = t00 + dt;
        const int win0 = dt * 8;
        float* prow = P32 + rr * PROW;
        const char* km = smem + KM_OFF;

        float vals[17];
        float mx = -INFINITY;
        #pragma unroll
        for (int k2 = 0; k2 < 17; ++k2) {
            const int cc = s16 + 16 * k2;
            float xv = -INFINITY;
            if (cc < WN) {
                const int c = win0 + cc;
                if (km[c]) xv = prow[c];
            }
            vals[k2] = xv;
            mx = fmaxf(mx, xv);
        }
        mx = fmaxf(mx, __shfl_xor(mx, 1));
        mx = fmaxf(mx, __shfl_xor(mx, 2));
        mx = fmaxf(mx, __shfl_xor(mx, 4));
        mx = fmaxf(mx, __shfl_xor(mx, 8));
        float sum = 0.f;
        #pragma unroll
        for (int k2 = 0; k2 < 17; ++k2) {
            const float p = (vals[k2] == -INFINITY) ? 0.f : __expf(vals[k2] - mx);
            vals[k2] = p;
            sum += p;
        }
        sum += __shfl_xor(sum, 1);
        sum += __shfl_xor(sum, 2);
        sum += __shfl_xor(sum, 4);
        sum += __shfl_xor(sum, 8);
        const float inv = 1.f / sum;

        float* ap = attn + (((size_t)(b * TSEQ + t) * NAG + n) * WN) * NH + h;
        #pragma unroll
        for (int k2 = 0; k2 < 17; ++k2) {
            const int cc = s16 + 16 * k2;
            if (cc < WN) {
                const float p = vals[k2] * inv;
                prow[win0 + cc] = p;
                ap[(size_t)cc * NH] = p;
            }
        }

        // in-place bf16 repack over all 288 cols (0 outside window)
        float pr[18];
        #pragma unroll
        for (int k2 = 0; k2 < 18; ++k2) {
            const int c = s16 + 16 * k2;
            pr[k2] = (c >= win0 && c < win0 + WN) ? prow[c] : 0.f;
        }
        __builtin_amdgcn_sched_barrier(0);
        asm volatile("s_waitcnt lgkmcnt(0)" ::: "memory");
        __builtin_amdgcn_sched_barrier(0);
        #pragma unroll
        for (int k2 = 0; k2 < 18; ++k2) {
            const int c = s16 + 16 * k2;
            *(unsigned short*)(smem + (size_t)rr * 1200 + 2 * c) = f2bf(pr[k2]);
        }
    }
    __syncthreads();

    // ---- PV: D[32 x 64]; A = P(bf16, LDS), B = vt (global, key-contiguous) ----
    {
        const int rfrag = wid & 1, dfrag = wid >> 1;
        const int arow = rfrag * 16 + (lane & 15);
        const int drow = dfrag * 16 + (lane & 15);       // d
        const unsigned short* vbase = vt + ((size_t)(b * 8 + h) * 64 + drow) * 2048;
        const int key0 = j0 * 8;
        f32x4 acc = (f32x4){0.f, 0.f, 0.f, 0.f};
        #pragma unroll
        for (int ms = 0; ms < 9; ++ms) {
            short8 afr = *(short8*)(smem + (size_t)arow * 1200 + ms * 64 + (lane >> 4) * 16);
            int kc = key0 + ms * 32 + (lane >> 4) * 8;
            kc = (kc < 0) ? 0 : ((kc > 2040) ? 2040 : kc);
            short8 bfr = *(const short8*)(vbase + kc);
            acc = __builtin_amdgcn_mfma_f32_16x16x32_bf16(afr, bfr, acc, 0, 0, 0);
        }
        const int r0 = rfrag * 16 + (lane >> 4) * 4;
        #pragma unroll
        for (int rg = 0; rg < 4; ++rg) {
            const int row = r0 + rg;
            const int t = t00 + (row >> 3), n = row & 7;
            out[((size_t)(b * TSEQ + t) * NAG + n) * EE + h * HD + drow] = acc[rg];
        }
    }
}

extern "C" void kernel_launch(void* const* d_in, const int* in_sizes, int n_in,
                              void* d_out, int out_size, void* d_ws, size_t ws_size,
                              hipStream_t stream) {
    const float* query = (const float*)d_in[0];
    const float* key   = (const float*)d_in[1];
    const float* value = (const float*)d_in[2];
    const unsigned char* kpm = (const unsigned char*)d_in[3];
    const float* Wq = (const float*)d_in[4];
    const float* bq = (const float*)d_in[5];
    const float* Wk = (const float*)d_in[6];
    const float* bk = (const float*)d_in[7];
    const float* Wv = (const float*)d_in[8];
    const float* bv = (const float*)d_in[9];

    float* out  = (float*)d_out;
    float* attn = out + (size_t)NBATCH * TSEQ * NAG * EE;

    unsigned short* qbf = (unsigned short*)d_ws;               // 4 MB bf16
    unsigned short* kbf = qbf + (size_t)4096 * EE;             // 4 MB
    unsigned short* vtb = kbf + (size_t)4096 * EE;             // 4 MB transposed V

    dim3 gp(32, 4, 3);
    proj_mfma_kernel<<<gp, 256, 0, stream>>>(query, key, value,
                                             Wq, Wk, Wv, bq, bk, bv,
                                             qbf, kbf, vtb);

    attn_mfma_kernel<<<1024, 512, 0, stream>>>(qbf, kbf, vtb, kpm, out, attn);
}

// Round 5
// 61.636 us; speedup vs baseline: 1.2218x; 1.2218x over previous
//
#include <hip/hip_runtime.h>
#include <hip/hip_bf16.h>

#define TSEQ 256
#define NBATCH 2
#define NAG 8
#define NH 8
#define HD 64
#define EE 512
#define WHALF 16
#define WW 33
#define WN 264   // WW*NAG

typedef __attribute__((ext_vector_type(8))) short short8;
typedef __attribute__((ext_vector_type(4))) short short4v;
typedef __attribute__((ext_vector_type(4))) float f32x4;

static __device__ __forceinline__ unsigned short f2bf(float f) {
    unsigned int u = __float_as_uint(f);
    unsigned int r = (u + 0x7FFFu + ((u >> 16) & 1u)) >> 16;
    return (unsigned short)r;
}

// ---------------- fused QKV projection GEMM (bf16 MFMA) -----------------
// BM=128, BN=128, BK=64, 4 waves (2x2, 64x64 each). z picks {q,k,v}.
// z==2 (v) writes TRANSPOSED vt[b][h][d][key=t*8+m] for attn PV B-fragments.
__global__ __launch_bounds__(256)
void proj_mfma_kernel(const float* __restrict__ xq, const float* __restrict__ xk,
                      const float* __restrict__ xv,
                      const float* __restrict__ Wq, const float* __restrict__ Wk,
                      const float* __restrict__ Wv,
                      const float* __restrict__ bq, const float* __restrict__ bk,
                      const float* __restrict__ bv,
                      unsigned short* __restrict__ oq, unsigned short* __restrict__ ok,
                      unsigned short* __restrict__ vt)
{
    __shared__ char As[128 * 128];   // 128 rows x 64 bf16 (swizzled)
    __shared__ char Bs[128 * 128];

    const float* x; const float* W; const float* bias; float scale;
    const int z = blockIdx.z;
    if (z == 0)      { x = xq; W = Wq; bias = bq; scale = 0.125f; }
    else if (z == 1) { x = xk; W = Wk; bias = bk; scale = 1.0f; }
    else             { x = xv; W = Wv; bias = bv; scale = 1.0f; }

    const int tid  = threadIdx.x;
    const int lane = tid & 63;
    const int wid  = tid >> 6;
    const int i0 = blockIdx.x * 128;
    const int f0 = blockIdx.y * 128;
    const int wr = wid >> 1, wc = wid & 1;

    f32x4 acc[4][4];
    #pragma unroll
    for (int m = 0; m < 4; ++m)
        #pragma unroll
        for (int n = 0; n < 4; ++n)
            acc[m][n] = (f32x4){0.f, 0.f, 0.f, 0.f};

    for (int k0 = 0; k0 < EE; k0 += 64) {
        #pragma unroll
        for (int it = 0; it < 8; ++it) {
            const int tt  = tid + it * 256;        // 0..2047
            const int row = tt >> 4, f4 = tt & 15;
            float4 v4 = *reinterpret_cast<const float4*>(x + (size_t)(i0 + row) * EE + k0 + f4 * 4);
            short4v s;
            s[0] = (short)f2bf(v4.x); s[1] = (short)f2bf(v4.y);
            s[2] = (short)f2bf(v4.z); s[3] = (short)f2bf(v4.w);
            *(short4v*)(As + row * 128 + ((f4 * 8) ^ ((row & 7) << 4))) = s;
        }
        #pragma unroll
        for (int it = 0; it < 8; ++it) {
            const int tt  = tid + it * 256;
            const int row = tt >> 4, f4 = tt & 15;
            float4 v4 = *reinterpret_cast<const float4*>(W + (size_t)(f0 + row) * EE + k0 + f4 * 4);
            short4v s;
            s[0] = (short)f2bf(v4.x); s[1] = (short)f2bf(v4.y);
            s[2] = (short)f2bf(v4.z); s[3] = (short)f2bf(v4.w);
            *(short4v*)(Bs + row * 128 + ((f4 * 8) ^ ((row & 7) << 4))) = s;
        }
        __syncthreads();

        #pragma unroll
        for (int ks = 0; ks < 2; ++ks) {
            short8 a[4], b[4];
            #pragma unroll
            for (int m = 0; m < 4; ++m) {
                const int row = wr * 64 + m * 16 + (lane & 15);
                a[m] = *(short8*)(As + row * 128 +
                                  ((ks * 64 + (lane >> 4) * 16) ^ ((row & 7) << 4)));
            }
            #pragma unroll
            for (int n = 0; n < 4; ++n) {
                const int row = wc * 64 + n * 16 + (lane & 15);
                b[n] = *(short8*)(Bs + row * 128 +
                                  ((ks * 64 + (lane >> 4) * 16) ^ ((row & 7) << 4)));
            }
            #pragma unroll
            for (int m = 0; m < 4; ++m)
                #pragma unroll
                for (int n = 0; n < 4; ++n)
                    acc[m][n] = __builtin_amdgcn_mfma_f32_16x16x32_bf16(a[m], b[n], acc[m][n], 0, 0, 0);
        }
        __syncthreads();
    }

    if (z < 2) {
        unsigned short* o = (z == 0) ? oq : ok;
        #pragma unroll
        for (int n = 0; n < 4; ++n) {
            const int col = f0 + wc * 64 + n * 16 + (lane & 15);
            const float bb = bias[col];
            #pragma unroll
            for (int m = 0; m < 4; ++m)
                #pragma unroll
                for (int rg = 0; rg < 4; ++rg) {
                    const int row = i0 + wr * 64 + m * 16 + (lane >> 4) * 4 + rg;
                    o[(size_t)row * EE + col] = f2bf((acc[m][n][rg] + bb) * scale);
                }
        }
    } else {
        // transposed store: vt[((b*8+h)*64+d)*2048 + (t*8+m)]
        #pragma unroll
        for (int n = 0; n < 4; ++n) {
            const int col = f0 + wc * 64 + n * 16 + (lane & 15);
            const int h = col >> 6, d = col & 63;
            const float bb = bias[col];
            #pragma unroll
            for (int m = 0; m < 4; ++m) {
                const int ibase = i0 + wr * 64 + m * 16 + (lane >> 4) * 4;
                const int bb_ = ibase >> 11;          // batch
                const int key = ibase & 2047;
                ushort4 s4;
                s4.x = f2bf(acc[m][n][0] + bb);
                s4.y = f2bf(acc[m][n][1] + bb);
                s4.z = f2bf(acc[m][n][2] + bb);
                s4.w = f2bf(acc[m][n][3] + bb);
                *(ushort4*)(vt + ((size_t)(bb_ * 8 + h) * 64 + d) * 2048 + key) = s4;
            }
        }
    }
}

// ---------------- MFMA windowed attention (no K/Q/V staging) -----------------
// grid: 1024 blocks, 512 threads.
// bid = ((g>>3)*8 + h)*8 + (g&7), g = ts*2+b  — all 8 h's of a group land on
// the SAME XCD (bid%8 == g%8) and are adjacent in dispatch order, so their
// interleaved 4B-of-32B attn writes merge in that XCD's L2 (full-line WB).
#define PROW 300                     // floats per P row (1200 B)
#define KM_OFF (32 * 1200)
#define SMEM2_BYTES (KM_OFF + 384)

__global__ __launch_bounds__(512)
void attn_mfma_kernel(const unsigned short* __restrict__ qb,
                      const unsigned short* __restrict__ kb,
                      const unsigned short* __restrict__ vt,
                      const unsigned char* __restrict__ kpm,
                      float* __restrict__ out,
                      float* __restrict__ attn)
{
    __shared__ char smem[SMEM2_BYTES];
    float* P32 = (float*)smem;

    const int bid = blockIdx.x;
    const int x8  = bid & 7;          // g % 8  (XCD selector)
    const int s   = bid >> 3;
    const int h   = s & 7;
    const int ghi = s >> 3;
    const int g   = ghi * 8 + x8;     // ts*2 + b
    const int b   = g & 1;
    const int ts  = g >> 1;
    const int t00 = ts * 4;
    const int j0  = t00 - WHALF;          // 36 j's -> 288 local keys
    const int tid = threadIdx.x;
    const int lane = tid & 63;
    const int wid  = tid >> 6;

    // ---- key-valid mask (read in softmax after barrier) ----
    if (tid < 288) {
        const int jj = tid >> 3, m = tid & 7;
        const int j = j0 + jj;
        smem[KM_OFF + tid] = (j >= 0 && j < TSEQ && kpm[(b * TSEQ + j) * NAG + m] == 0) ? 1 : 0;
    }

    // ---- QK^T: D[32 x 288] from global fragments ----
    {
        const int rfrag = wid & 1;                     // wave's parity fixes rfrag
        const int arow = rfrag * 16 + (lane & 15);
        const int t = t00 + (arow >> 3), n = arow & 7;
        const unsigned short* qbase = qb + ((size_t)(b * TSEQ + t) * NAG + n) * EE + h * HD;
        short8 aq0 = *(const short8*)(qbase + (lane >> 4) * 8);
        short8 aq1 = *(const short8*)(qbase + 32 + (lane >> 4) * 8);

        #pragma unroll
        for (int i = 0; i < 5; ++i) {
            const int cf = (wid >> 1) + 4 * i;         // pair p = wid + 8*i
            if (cf >= 18) break;
            const int krow = cf * 16 + (lane & 15);
            int j = j0 + (krow >> 3);
            j = (j < 0) ? 0 : ((j > TSEQ - 1) ? TSEQ - 1 : j);
            const int m = krow & 7;
            const unsigned short* kbase = kb + ((size_t)(b * TSEQ + j) * NAG + m) * EE + h * HD;
            f32x4 a = (f32x4){0.f, 0.f, 0.f, 0.f};
            a = __builtin_amdgcn_mfma_f32_16x16x32_bf16(aq0, *(const short8*)(kbase + (lane >> 4) * 8), a, 0, 0, 0);
            a = __builtin_amdgcn_mfma_f32_16x16x32_bf16(aq1, *(const short8*)(kbase + 32 + (lane >> 4) * 8), a, 0, 0, 0);
            const int col = cf * 16 + (lane & 15);
            const int r0 = rfrag * 16 + (lane >> 4) * 4;
            #pragma unroll
            for (int rg = 0; rg < 4; ++rg)
                P32[(r0 + rg) * PROW + col] = a[rg];
        }
    }
    __syncthreads();

    // ---- softmax over 264-window + attn store + bf16 repack ----
    {
        const int rr = tid >> 4, s16 = tid & 15;
        const int dt = rr >> 3, n = rr & 7;
        const int t = t00 + dt;
        const int win0 = dt * 8;
        float* prow = P32 + rr * PROW;
        const char* km = smem + KM_OFF;

        float vals[17];
        float mx = -INFINITY;
        #pragma unroll
        for (int k2 = 0; k2 < 17; ++k2) {
            const int cc = s16 + 16 * k2;
            float xv = -INFINITY;
            if (cc < WN) {
                const int c = win0 + cc;
                if (km[c]) xv = prow[c];
            }
            vals[k2] = xv;
            mx = fmaxf(mx, xv);
        }
        mx = fmaxf(mx, __shfl_xor(mx, 1));
        mx = fmaxf(mx, __shfl_xor(mx, 2));
        mx = fmaxf(mx, __shfl_xor(mx, 4));
        mx = fmaxf(mx, __shfl_xor(mx, 8));
        float sum = 0.f;
        #pragma unroll
        for (int k2 = 0; k2 < 17; ++k2) {
            const float p = (vals[k2] == -INFINITY) ? 0.f : __expf(vals[k2] - mx);
            vals[k2] = p;
            sum += p;
        }
        sum += __shfl_xor(sum, 1);
        sum += __shfl_xor(sum, 2);
        sum += __shfl_xor(sum, 4);
        sum += __shfl_xor(sum, 8);
        const float inv = 1.f / sum;

        float* ap = attn + (((size_t)(b * TSEQ + t) * NAG + n) * WN) * NH + h;
        #pragma unroll
        for (int k2 = 0; k2 < 17; ++k2) {
            const int cc = s16 + 16 * k2;
            if (cc < WN) {
                const float p = vals[k2] * inv;
                prow[win0 + cc] = p;
                ap[(size_t)cc * NH] = p;
            }
        }

        // in-place bf16 repack over all 288 cols (0 outside window)
        float pr[18];
        #pragma unroll
        for (int k2 = 0; k2 < 18; ++k2) {
            const int c = s16 + 16 * k2;
            pr[k2] = (c >= win0 && c < win0 + WN) ? prow[c] : 0.f;
        }
        __builtin_amdgcn_sched_barrier(0);
        asm volatile("s_waitcnt lgkmcnt(0)" ::: "memory");
        __builtin_amdgcn_sched_barrier(0);
        #pragma unroll
        for (int k2 = 0; k2 < 18; ++k2) {
            const int c = s16 + 16 * k2;
            *(unsigned short*)(smem + (size_t)rr * 1200 + 2 * c) = f2bf(pr[k2]);
        }
    }
    __syncthreads();

    // ---- PV: D[32 x 64]; A = P(bf16, LDS), B = vt (global, key-contiguous) ----
    {
        const int rfrag = wid & 1, dfrag = wid >> 1;
        const int arow = rfrag * 16 + (lane & 15);
        const int drow = dfrag * 16 + (lane & 15);       // d
        const unsigned short* vbase = vt + ((size_t)(b * 8 + h) * 64 + drow) * 2048;
        const int key0 = j0 * 8;
        f32x4 acc = (f32x4){0.f, 0.f, 0.f, 0.f};
        #pragma unroll
        for (int ms = 0; ms < 9; ++ms) {
            short8 afr = *(short8*)(smem + (size_t)arow * 1200 + ms * 64 + (lane >> 4) * 16);
            int kc = key0 + ms * 32 + (lane >> 4) * 8;
            kc = (kc < 0) ? 0 : ((kc > 2040) ? 2040 : kc);
            short8 bfr = *(const short8*)(vbase + kc);
            acc = __builtin_amdgcn_mfma_f32_16x16x32_bf16(afr, bfr, acc, 0, 0, 0);
        }
        const int r0 = rfrag * 16 + (lane >> 4) * 4;
        #pragma unroll
        for (int rg = 0; rg < 4; ++rg) {
            const int row = r0 + rg;
            const int t = t00 + (row >> 3), n = row & 7;
            out[((size_t)(b * TSEQ + t) * NAG + n) * EE + h * HD + drow] = acc[rg];
        }
    }
}

extern "C" void kernel_launch(void* const* d_in, const int* in_sizes, int n_in,
                              void* d_out, int out_size, void* d_ws, size_t ws_size,
                              hipStream_t stream) {
    const float* query = (const float*)d_in[0];
    const float* key   = (const float*)d_in[1];
    const float* value = (const float*)d_in[2];
    const unsigned char* kpm = (const unsigned char*)d_in[3];
    const float* Wq = (const float*)d_in[4];
    const float* bq = (const float*)d_in[5];
    const float* Wk = (const float*)d_in[6];
    const float* bk = (const float*)d_in[7];
    const float* Wv = (const float*)d_in[8];
    const float* bv = (const float*)d_in[9];

    float* out  = (float*)d_out;
    float* attn = out + (size_t)NBATCH * TSEQ * NAG * EE;

    unsigned short* qbf = (unsigned short*)d_ws;               // 4 MB bf16
    unsigned short* kbf = qbf + (size_t)4096 * EE;             // 4 MB
    unsigned short* vtb = kbf + (size_t)4096 * EE;             // 4 MB transposed V

    dim3 gp(32, 4, 3);
    proj_mfma_kernel<<<gp, 256, 0, stream>>>(query, key, value,
                                             Wq, Wk, Wv, bq, bk, bv,
                                             qbf, kbf, vtb);

    attn_mfma_kernel<<<1024, 512, 0, stream>>>(qbf, kbf, vtb, kpm, out, attn);
}